// Round 10
// baseline (141.262 us; speedup 1.0000x reference)
//
#include <hip/hip_runtime.h>

#define B_   128
#define L_   26
#define C1_  128
#define C2_  64
#define K1_  7
#define K2_  5
#define NPOS 25
#define FEAT (L_*C2_)            // 1664
#define NPAIR (NPOS*(NPOS+1)/2)  // 325

#define HROW 132                 // h1s row stride (4-aligned, <=2-way bank = free)
#define W2ROW 644                // w2s row stride (4-aligned, bank-spread)

// ---------------------------------------------------------------------------
// Kernel A: conv1 -> conv2 -> featT[u][b], register-tiled stage 2.
// grid = 256 = (b, c2-half of 32); block = 128 (2 waves); 1 block/CU.
// LDS: w2 half [32][644] 82.4K + h1 [30][132] 15.8K + w1 14K = ~113K.
// Stage-2: thread = (c2-quad, l-pair): per (k, c1-quad): 6 ds_read_b128
// -> 32 FMA. 960 reads/thread for 8 outputs (120/output vs 240 before).
// ---------------------------------------------------------------------------
__global__ __launch_bounds__(128) void conv_kernel(
    const int*   __restrict__ x,
    const float* __restrict__ w1, const float* __restrict__ b1,
    const float* __restrict__ w2, const float* __restrict__ b2,
    float* __restrict__ featT, int* __restrict__ counter)
{
    __shared__ float w2s[32*W2ROW];         // 82432B
    __shared__ float h1s[30*HROW];          // 15840B
    __shared__ float w1s[4*K1_*C1_];        // [nt][k][c1], 14336B
    __shared__ int   xs[L_];

    const int bid  = blockIdx.x;
    const int b    = bid >> 1;
    const int half = bid & 1;
    const int t    = threadIdx.x;

    if (bid == 0 && t == 0) *counter = 0;   // reset pair-counter for kernel B

    if (t < L_) xs[t] = x[b*L_ + t];
    for (int i = t; i < HROW; i += 128) {   // zero pad rows 0,1,28,29
        h1s[0*HROW+i] = 0.f; h1s[1*HROW+i] = 0.f;
        h1s[28*HROW+i] = 0.f; h1s[29*HROW+i] = 0.f;
    }

    // stage w1 transposed: global [c1][nt][k] -> lds [nt][k][c1]
    for (int i = t; i < C1_*4*K1_; i += 128) {
        const int c1  = i / (4*K1_);
        const int rem = i - c1*(4*K1_);
        const int nt  = rem / K1_;
        const int k   = rem - nt*K1_;
        w1s[(nt*K1_ + k)*C1_ + c1] = w1[i];
    }

    // stage w2 half transposed: global [c2][c1][k] -> w2s[c2][k][c1]
    {
        const float* src = w2 + half*32*C1_*K2_;
        #pragma unroll
        for (int i = 0; i < 32; ++i) {
            const int p  = t + i*128;        // (c2,c1) pair index 0..4095
            const int c2 = p >> 7;
            const int c1 = p & 127;
            const float* s5 = src + p*5;
            float* dst = &w2s[c2*W2ROW + c1];
            dst[0*C1_] = s5[0]; dst[1*C1_] = s5[1]; dst[2*C1_] = s5[2];
            dst[3*C1_] = s5[3]; dst[4*C1_] = s5[4];
        }
    }
    __syncthreads();

    // stage 1: h1s[l+2][c1] = relu(b1 + sum_k w1[c1][x[l+k-3]][k])
    for (int idx = t; idx < C1_*L_; idx += 128) {
        const int c1 = idx & 127;
        const int l  = idx >> 7;
        float s = b1[c1];
        #pragma unroll
        for (int k = 0; k < K1_; ++k) {
            const int pos = l + k - 3;
            if (pos >= 0 && pos < L_)
                s += w1s[(xs[pos]*K1_ + k)*C1_ + c1];
        }
        h1s[(l+2)*HROW + c1] = fmaxf(s, 0.f);
    }
    __syncthreads();

    // stage 2: t < 104: c2t = t/13 (quad of c2), lt = t%13 (l-pair)
    if (t < 104) {
        const int c2t = t / 13;
        const int lt  = t - c2t*13;
        const int l0  = 2*lt, l1 = l0 + 1;

        float acc00=0.f, acc01=0.f, acc02=0.f, acc03=0.f;
        float acc10=0.f, acc11=0.f, acc12=0.f, acc13=0.f;
        const float* wbase = &w2s[(c2t*4)*W2ROW];

        for (int k = 0; k < K2_; ++k) {
            // h row for pos l+k-2 is row l+k (rows 0,1,28,29 are zero pads)
            const float4* hr0 = (const float4*)&h1s[(l0 + k)*HROW];
            const float4* hr1 = (const float4*)&h1s[(l1 + k)*HROW];
            const float*  wk  = wbase + k*C1_;
            #pragma unroll 4
            for (int q = 0; q < 32; ++q) {
                const float4 h0 = hr0[q];
                const float4 h1v = hr1[q];
                const float4 w0 = *(const float4*)&wk[0*W2ROW + q*4];
                const float4 w1v= *(const float4*)&wk[1*W2ROW + q*4];
                const float4 w2v= *(const float4*)&wk[2*W2ROW + q*4];
                const float4 w3 = *(const float4*)&wk[3*W2ROW + q*4];
                acc00 += w0.x*h0.x + w0.y*h0.y + w0.z*h0.z + w0.w*h0.w;
                acc01 += w1v.x*h0.x + w1v.y*h0.y + w1v.z*h0.z + w1v.w*h0.w;
                acc02 += w2v.x*h0.x + w2v.y*h0.y + w2v.z*h0.z + w2v.w*h0.w;
                acc03 += w3.x*h0.x + w3.y*h0.y + w3.z*h0.z + w3.w*h0.w;
                acc10 += w0.x*h1v.x + w0.y*h1v.y + w0.z*h1v.z + w0.w*h1v.w;
                acc11 += w1v.x*h1v.x + w1v.y*h1v.y + w1v.z*h1v.z + w1v.w*h1v.w;
                acc12 += w2v.x*h1v.x + w2v.y*h1v.y + w2v.z*h1v.z + w2v.w*h1v.w;
                acc13 += w3.x*h1v.x + w3.y*h1v.y + w3.z*h1v.z + w3.w*h1v.w;
            }
        }

        const int c2g = half*32 + c2t*4;
        const float bb0 = b2[c2g+0], bb1 = b2[c2g+1],
                    bb2 = b2[c2g+2], bb3 = b2[c2g+3];
        float* f0 = &featT[(l0*C2_ + c2g)*B_ + b];
        float* f1 = &featT[(l1*C2_ + c2g)*B_ + b];
        f0[0*B_] = fmaxf(acc00 + bb0, 0.f);
        f0[1*B_] = fmaxf(acc01 + bb1, 0.f);
        f0[2*B_] = fmaxf(acc02 + bb2, 0.f);
        f0[3*B_] = fmaxf(acc03 + bb3, 0.f);
        f1[0*B_] = fmaxf(acc10 + bb0, 0.f);
        f1[1*B_] = fmaxf(acc11 + bb1, 0.f);
        f1[2*B_] = fmaxf(acc12 + bb2, 0.f);
        f1[3*B_] = fmaxf(acc13 + bb3, 0.f);
    }
}

// ---------------------------------------------------------------------------
// Kernel B: pair blocks (R9 structure, unchanged math) + last-block fin.
// ---------------------------------------------------------------------------
__global__ __launch_bounds__(256) void reg_kernel(
    const float* __restrict__ featT,
    const float* __restrict__ rw, const float* __restrict__ rb,
    float* __restrict__ part, int* __restrict__ counter,
    float* __restrict__ out)
{
    __shared__ float ws[64*64];     // 16KB
    __shared__ float red0[256], red1[256];
    __shared__ int   isLast;
    const int t  = threadIdx.x;
    const int b0 = t & 63;
    const int wv = t >> 6;          // 0..3
    const int bid = blockIdx.x;

    float acc0 = 0.f, acc1 = 0.f;

    if (bid == NPAIR) {             // first order + const
        const int u0 = wv * (FEAT/4);
        for (int u = u0; u < u0 + FEAT/4; ++u) {
            const float w = rw[1 + u];              // wave-uniform -> s_load
            acc0 += featT[u*B_ + b0]      * w;      // coalesced
            acc1 += featT[u*B_ + b0 + 64] * w;
        }
        if (wv == 0) { const float c = rw[0] + rb[0]; acc0 += c; acc1 += c; }
    } else {
        int i = 0, r = bid;
        while (r >= NPOS - i) { r -= NPOS - i; ++i; }
        const int j = i + 1 + r;

        const int stride = (NPOS - i) * 64;
        const int base   = 1 + FEAT + 4096*(NPOS*i - (i*(i-1))/2)
                         + (j - i - 1)*64;

        // stage W_ij (64 rows x 64 q) coalesced over q
        #pragma unroll
        for (int k = 0; k < 16; ++k) {
            const int idx = t + k*256;
            ws[idx] = rw[base + (idx >> 6)*stride + (idx & 63)];
        }
        __syncthreads();

        const int p0 = wv * 16;
        float sp0[16], sp1[16];
        #pragma unroll
        for (int pp = 0; pp < 16; ++pp) { sp0[pp] = 0.f; sp1[pp] = 0.f; }

        const float* fj = &featT[j*64*B_ + b0];
        #pragma unroll 4
        for (int g = 0; g < 16; ++g) {
            const float f00 = fj[(g*4+0)*B_],      f01 = fj[(g*4+1)*B_],
                        f02 = fj[(g*4+2)*B_],      f03 = fj[(g*4+3)*B_];
            const float f10 = fj[(g*4+0)*B_ + 64], f11 = fj[(g*4+1)*B_ + 64],
                        f12 = fj[(g*4+2)*B_ + 64], f13 = fj[(g*4+3)*B_ + 64];
            #pragma unroll
            for (int pp = 0; pp < 16; ++pp) {
                const float4 w = *(const float4*)&ws[(p0 + pp)*64 + g*4];
                sp0[pp] += w.x*f00 + w.y*f01 + w.z*f02 + w.w*f03;
                sp1[pp] += w.x*f10 + w.y*f11 + w.z*f12 + w.w*f13;
            }
        }

        const float* fi = &featT[(i*64 + p0)*B_ + b0];
        #pragma unroll
        for (int pp = 0; pp < 16; ++pp) {
            acc0 += fi[pp*B_]      * sp0[pp];
            acc1 += fi[pp*B_ + 64] * sp1[pp];
        }
    }

    red0[t] = acc0;
    red1[t] = acc1;
    __syncthreads();
    if (t < B_) {
        const int bb = t & 63;
        const float* rr = (t < 64) ? red0 : red1;
        part[bid*B_ + t] = (rr[bb] + rr[64+bb]) + (rr[128+bb] + rr[192+bb]);
    }

    // ---- last-block finalize (replaces fin kernel) ----
    __threadfence();                 // release part[] stores
    __syncthreads();
    if (t == 0) isLast = (atomicAdd(counter, 1) == NPAIR);
    __syncthreads();
    if (isLast) {
        __threadfence();             // acquire other blocks' part[] stores
        if (t < B_) {
            float s0 = 0.f, s1 = 0.f, s2 = 0.f, s3 = 0.f;
            int p = 0;
            for (; p + 4 <= NPAIR + 1; p += 4) {
                s0 += part[(p+0)*B_ + t];
                s1 += part[(p+1)*B_ + t];
                s2 += part[(p+2)*B_ + t];
                s3 += part[(p+3)*B_ + t];
            }
            for (; p < NPAIR + 1; ++p) s0 += part[p*B_ + t];
            out[t] = (s0 + s1) + (s2 + s3);
        }
    }
}

// ---------------------------------------------------------------------------
extern "C" void kernel_launch(void* const* d_in, const int* in_sizes, int n_in,
                              void* d_out, int out_size, void* d_ws, size_t ws_size,
                              hipStream_t stream)
{
    const int*   x  = (const int*)  d_in[0];
    const float* w1 = (const float*)d_in[1];
    const float* b1 = (const float*)d_in[2];
    const float* w2 = (const float*)d_in[3];
    const float* b2 = (const float*)d_in[4];
    const float* rw = (const float*)d_in[5];
    const float* rb = (const float*)d_in[6];
    float* out     = (float*)d_out;
    float* featT   = (float*)d_ws;                      // 851968 B
    float* part    = (float*)((char*)d_ws + 851968);    // 166912 B
    int*   counter = (int*)  ((char*)d_ws + 851968 + 166912);

    conv_kernel<<<dim3(256), dim3(128), 0, stream>>>(x, w1, b1, w2, b2,
                                                     featT, counter);
    reg_kernel <<<dim3(NPAIR+1), dim3(256), 0, stream>>>(featT, rw, rb,
                                                         part, counter, out);
}

// Round 11
// 127.021 us; speedup vs baseline: 1.1121x; 1.1121x over previous
//
#include <hip/hip_runtime.h>

#define B_   128
#define L_   26
#define C1_  128
#define C2_  64
#define K1_  7
#define K2_  5
#define NPOS 25
#define FEAT (L_*C2_)            // 1664
#define NPAIR (NPOS*(NPOS+1)/2)  // 325

#define HROW 132                 // h1s row stride (4-aligned, <=2-way bank = free)
#define W2ROW 644                // w2s row stride (4-aligned, bank-spread)

// ---------------------------------------------------------------------------
// Kernel A: conv1 -> conv2 -> featT[u][b], register-tiled stage 2.
// (byte-identical to round 10 except counter removed)
// grid = 256 = (b, c2-half of 32); block = 128 (2 waves); 1 block/CU.
// ---------------------------------------------------------------------------
__global__ __launch_bounds__(128) void conv_kernel(
    const int*   __restrict__ x,
    const float* __restrict__ w1, const float* __restrict__ b1,
    const float* __restrict__ w2, const float* __restrict__ b2,
    float* __restrict__ featT)
{
    __shared__ float w2s[32*W2ROW];         // 82432B
    __shared__ float h1s[30*HROW];          // 15840B
    __shared__ float w1s[4*K1_*C1_];        // [nt][k][c1], 14336B
    __shared__ int   xs[L_];

    const int bid  = blockIdx.x;
    const int b    = bid >> 1;
    const int half = bid & 1;
    const int t    = threadIdx.x;

    if (t < L_) xs[t] = x[b*L_ + t];
    for (int i = t; i < HROW; i += 128) {   // zero pad rows 0,1,28,29
        h1s[0*HROW+i] = 0.f; h1s[1*HROW+i] = 0.f;
        h1s[28*HROW+i] = 0.f; h1s[29*HROW+i] = 0.f;
    }

    // stage w1 transposed: global [c1][nt][k] -> lds [nt][k][c1]
    for (int i = t; i < C1_*4*K1_; i += 128) {
        const int c1  = i / (4*K1_);
        const int rem = i - c1*(4*K1_);
        const int nt  = rem / K1_;
        const int k   = rem - nt*K1_;
        w1s[(nt*K1_ + k)*C1_ + c1] = w1[i];
    }

    // stage w2 half transposed: global [c2][c1][k] -> w2s[c2][k][c1]
    {
        const float* src = w2 + half*32*C1_*K2_;
        #pragma unroll
        for (int i = 0; i < 32; ++i) {
            const int p  = t + i*128;        // (c2,c1) pair index 0..4095
            const int c2 = p >> 7;
            const int c1 = p & 127;
            const float* s5 = src + p*5;
            float* dst = &w2s[c2*W2ROW + c1];
            dst[0*C1_] = s5[0]; dst[1*C1_] = s5[1]; dst[2*C1_] = s5[2];
            dst[3*C1_] = s5[3]; dst[4*C1_] = s5[4];
        }
    }
    __syncthreads();

    // stage 1: h1s[l+2][c1] = relu(b1 + sum_k w1[c1][x[l+k-3]][k])
    for (int idx = t; idx < C1_*L_; idx += 128) {
        const int c1 = idx & 127;
        const int l  = idx >> 7;
        float s = b1[c1];
        #pragma unroll
        for (int k = 0; k < K1_; ++k) {
            const int pos = l + k - 3;
            if (pos >= 0 && pos < L_)
                s += w1s[(xs[pos]*K1_ + k)*C1_ + c1];
        }
        h1s[(l+2)*HROW + c1] = fmaxf(s, 0.f);
    }
    __syncthreads();

    // stage 2: t < 104: c2t = t/13 (quad of c2), lt = t%13 (l-pair)
    if (t < 104) {
        const int c2t = t / 13;
        const int lt  = t - c2t*13;
        const int l0  = 2*lt, l1 = l0 + 1;

        float acc00=0.f, acc01=0.f, acc02=0.f, acc03=0.f;
        float acc10=0.f, acc11=0.f, acc12=0.f, acc13=0.f;
        const float* wbase = &w2s[(c2t*4)*W2ROW];

        for (int k = 0; k < K2_; ++k) {
            const float4* hr0 = (const float4*)&h1s[(l0 + k)*HROW];
            const float4* hr1 = (const float4*)&h1s[(l1 + k)*HROW];
            const float*  wk  = wbase + k*C1_;
            #pragma unroll 4
            for (int q = 0; q < 32; ++q) {
                const float4 h0 = hr0[q];
                const float4 h1v = hr1[q];
                const float4 w0 = *(const float4*)&wk[0*W2ROW + q*4];
                const float4 w1v= *(const float4*)&wk[1*W2ROW + q*4];
                const float4 w2v= *(const float4*)&wk[2*W2ROW + q*4];
                const float4 w3 = *(const float4*)&wk[3*W2ROW + q*4];
                acc00 += w0.x*h0.x + w0.y*h0.y + w0.z*h0.z + w0.w*h0.w;
                acc01 += w1v.x*h0.x + w1v.y*h0.y + w1v.z*h0.z + w1v.w*h0.w;
                acc02 += w2v.x*h0.x + w2v.y*h0.y + w2v.z*h0.z + w2v.w*h0.w;
                acc03 += w3.x*h0.x + w3.y*h0.y + w3.z*h0.z + w3.w*h0.w;
                acc10 += w0.x*h1v.x + w0.y*h1v.y + w0.z*h1v.z + w0.w*h1v.w;
                acc11 += w1v.x*h1v.x + w1v.y*h1v.y + w1v.z*h1v.z + w1v.w*h1v.w;
                acc12 += w2v.x*h1v.x + w2v.y*h1v.y + w2v.z*h1v.z + w2v.w*h1v.w;
                acc13 += w3.x*h1v.x + w3.y*h1v.y + w3.z*h1v.z + w3.w*h1v.w;
            }
        }

        const int c2g = half*32 + c2t*4;
        const float bb0 = b2[c2g+0], bb1 = b2[c2g+1],
                    bb2 = b2[c2g+2], bb3 = b2[c2g+3];
        float* f0 = &featT[(l0*C2_ + c2g)*B_ + b];
        float* f1 = &featT[(l1*C2_ + c2g)*B_ + b];
        f0[0*B_] = fmaxf(acc00 + bb0, 0.f);
        f0[1*B_] = fmaxf(acc01 + bb1, 0.f);
        f0[2*B_] = fmaxf(acc02 + bb2, 0.f);
        f0[3*B_] = fmaxf(acc03 + bb3, 0.f);
        f1[0*B_] = fmaxf(acc10 + bb0, 0.f);
        f1[1*B_] = fmaxf(acc11 + bb1, 0.f);
        f1[2*B_] = fmaxf(acc12 + bb2, 0.f);
        f1[3*B_] = fmaxf(acc13 + bb3, 0.f);
    }
}

// ---------------------------------------------------------------------------
// Kernel B: EXACT round-9 version (no fence, no counter, plain part[] write).
// ---------------------------------------------------------------------------
__global__ __launch_bounds__(256) void reg_kernel(
    const float* __restrict__ featT,
    const float* __restrict__ rw, const float* __restrict__ rb,
    float* __restrict__ part)
{
    __shared__ float ws[64*64];     // 16KB
    __shared__ float red0[256], red1[256];
    const int t  = threadIdx.x;
    const int b0 = t & 63;
    const int wv = t >> 6;          // 0..3
    const int bid = blockIdx.x;

    float acc0 = 0.f, acc1 = 0.f;

    if (bid == NPAIR) {             // first order + const
        const int u0 = wv * (FEAT/4);
        for (int u = u0; u < u0 + FEAT/4; ++u) {
            const float w = rw[1 + u];              // wave-uniform -> s_load
            acc0 += featT[u*B_ + b0]      * w;      // coalesced
            acc1 += featT[u*B_ + b0 + 64] * w;
        }
        if (wv == 0) { const float c = rw[0] + rb[0]; acc0 += c; acc1 += c; }
    } else {
        int i = 0, r = bid;
        while (r >= NPOS - i) { r -= NPOS - i; ++i; }
        const int j = i + 1 + r;

        const int stride = (NPOS - i) * 64;
        const int base   = 1 + FEAT + 4096*(NPOS*i - (i*(i-1))/2)
                         + (j - i - 1)*64;

        // stage W_ij (64 rows x 64 q) coalesced over q
        #pragma unroll
        for (int k = 0; k < 16; ++k) {
            const int idx = t + k*256;
            ws[idx] = rw[base + (idx >> 6)*stride + (idx & 63)];
        }
        __syncthreads();

        const int p0 = wv * 16;
        float sp0[16], sp1[16];
        #pragma unroll
        for (int pp = 0; pp < 16; ++pp) { sp0[pp] = 0.f; sp1[pp] = 0.f; }

        const float* fj = &featT[j*64*B_ + b0];
        #pragma unroll 4
        for (int g = 0; g < 16; ++g) {
            const float f00 = fj[(g*4+0)*B_],      f01 = fj[(g*4+1)*B_],
                        f02 = fj[(g*4+2)*B_],      f03 = fj[(g*4+3)*B_];
            const float f10 = fj[(g*4+0)*B_ + 64], f11 = fj[(g*4+1)*B_ + 64],
                        f12 = fj[(g*4+2)*B_ + 64], f13 = fj[(g*4+3)*B_ + 64];
            #pragma unroll
            for (int pp = 0; pp < 16; ++pp) {
                const float4 w = *(const float4*)&ws[(p0 + pp)*64 + g*4];
                sp0[pp] += w.x*f00 + w.y*f01 + w.z*f02 + w.w*f03;
                sp1[pp] += w.x*f10 + w.y*f11 + w.z*f12 + w.w*f13;
            }
        }

        const float* fi = &featT[(i*64 + p0)*B_ + b0];
        #pragma unroll
        for (int pp = 0; pp < 16; ++pp) {
            acc0 += fi[pp*B_]      * sp0[pp];
            acc1 += fi[pp*B_ + 64] * sp1[pp];
        }
    }

    red0[t] = acc0;
    red1[t] = acc1;
    __syncthreads();
    if (t < B_) {
        const int bb = t & 63;
        const float* rr = (t < 64) ? red0 : red1;
        part[bid*B_ + t] = (rr[bb] + rr[64+bb]) + (rr[128+bb] + rr[192+bb]);
    }
}

// ---------------------------------------------------------------------------
// finalize: out[b] = sum over 326 partials (coalesced, 4-way ILP)
// ---------------------------------------------------------------------------
__global__ __launch_bounds__(128) void fin_kernel(
    const float* __restrict__ part, float* __restrict__ out)
{
    const int b = threadIdx.x;
    float s0 = 0.f, s1 = 0.f, s2 = 0.f, s3 = 0.f;
    int p = 0;
    for (; p + 4 <= NPAIR + 1; p += 4) {
        s0 += part[(p+0)*B_ + b];
        s1 += part[(p+1)*B_ + b];
        s2 += part[(p+2)*B_ + b];
        s3 += part[(p+3)*B_ + b];
    }
    for (; p < NPAIR + 1; ++p) s0 += part[p*B_ + b];
    out[b] = (s0 + s1) + (s2 + s3);
}

// ---------------------------------------------------------------------------
extern "C" void kernel_launch(void* const* d_in, const int* in_sizes, int n_in,
                              void* d_out, int out_size, void* d_ws, size_t ws_size,
                              hipStream_t stream)
{
    const int*   x  = (const int*)  d_in[0];
    const float* w1 = (const float*)d_in[1];
    const float* b1 = (const float*)d_in[2];
    const float* w2 = (const float*)d_in[3];
    const float* b2 = (const float*)d_in[4];
    const float* rw = (const float*)d_in[5];
    const float* rb = (const float*)d_in[6];
    float* out   = (float*)d_out;
    float* featT = (float*)d_ws;                     // 851968 B
    float* part  = (float*)((char*)d_ws + 851968);   // 166912 B

    conv_kernel<<<dim3(256), dim3(128), 0, stream>>>(x, w1, b1, w2, b2, featT);
    reg_kernel <<<dim3(NPAIR+1), dim3(256), 0, stream>>>(featT, rw, rb, part);
    fin_kernel <<<dim3(1), dim3(128), 0, stream>>>(part, out);
}

// Round 12
// 126.896 us; speedup vs baseline: 1.1132x; 1.0010x over previous
//
#include <hip/hip_runtime.h>

#define B_   128
#define L_   26
#define C1_  128
#define C2_  64
#define K1_  7
#define K2_  5
#define NPOS 25
#define FEAT (L_*C2_)            // 1664
#define NPAIR (NPOS*(NPOS+1)/2)  // 325
#define HR   30                  // padded h rows: row = pos+2, rows 0,1,28,29 zero

// ws layout (bytes):
//   h1g  [c1][30][b] : 128*30*128*4 = 1,966,080   at 0
//   featT[u][b]      : 1664*128*4   =   851,968   at 1,966,080
//   part [326][b]    : 326*128*4    =   166,912   at 2,818,048

// ---------------------------------------------------------------------------
// Kernel S: stage-1 conv to global h1g[c1][row][b] (+ zero pad rows).
// blocks 0..103: (l, c1-quarter of 32); blocks 104..119: pad-row zeroing.
// block = 128 threads = 128 b (lane-coalesced stores).
// ---------------------------------------------------------------------------
__global__ __launch_bounds__(128) void s_kernel(
    const int*   __restrict__ x,
    const float* __restrict__ w1, const float* __restrict__ b1,
    float* __restrict__ h1g)
{
    const int bid = blockIdx.x;
    const int t   = threadIdx.x;     // = b

    if (bid >= 104) {                // zero pad rows
        const int z   = bid - 104;   // 0..15
        const int c1q = z >> 2;
        const int pr  = z & 3;
        const int row = (pr < 2) ? pr : 26 + pr;   // 0,1,28,29
        #pragma unroll
        for (int ci = 0; ci < 32; ++ci)
            h1g[((c1q*32 + ci)*HR + row)*B_ + t] = 0.f;
        return;
    }

    const int l   = bid % 26;
    const int c1q = bid / 26;        // 0..3

    __shared__ float w1s[4*K1_*32]; // [nt][k][ci] for this c1-chunk, 896 floats
    for (int i = t; i < 4*K1_*32; i += 128) {
        const int ci  = i / (4*K1_);
        const int rem = i - ci*(4*K1_);      // nt*7+k
        w1s[rem*32 + ci] = w1[(c1q*32 + ci)*(4*K1_) + rem];
    }
    __syncthreads();

    // per-lane x values for the 7 taps (uniform validity: l is block-uniform)
    int xv[K1_];
    #pragma unroll
    for (int k = 0; k < K1_; ++k) {
        const int pos = l + k - 3;
        xv[k] = (pos >= 0 && pos < L_) ? x[t*L_ + pos] : 0;
    }

    for (int ci = 0; ci < 32; ++ci) {
        float s = b1[c1q*32 + ci];
        #pragma unroll
        for (int k = 0; k < K1_; ++k) {
            const int pos = l + k - 3;
            if (pos >= 0 && pos < L_)
                s += w1s[(xv[k]*K1_ + k)*32 + ci];
        }
        h1g[((c1q*32 + ci)*HR + (l + 2))*B_ + t] = fmaxf(s, 0.f);
    }
}

// ---------------------------------------------------------------------------
// Kernel G: conv2 as GEMM. grid = 26 l * 8 c2-octets = 208 blocks; block 256.
// wave = K-quarter (32 c1); lane = b0; thread covers b0 and b0+64.
// W: LDS [k][c1][c2i] -> 2 broadcast b128 per (c1,k) (wave-uniform).
// H: h1g coalesced global dword (L2-resident).
// Split-K reduced in-block via LDS; writes featT[u][b] = relu(.+b2).
// ---------------------------------------------------------------------------
__global__ __launch_bounds__(256) void g_kernel(
    const float* __restrict__ h1g,
    const float* __restrict__ w2, const float* __restrict__ b2,
    float* __restrict__ featT)
{
    __shared__ float w2s[K2_*C1_*8];     // [k][c1][c2i], 5120 floats = 20KB
    __shared__ float red[4*8*B_];        // [kq][c2i][b], 4096 floats = 16KB

    const int bid = blockIdx.x;
    const int l   = bid % 26;
    const int c2o = bid / 26;            // 0..7
    const int t   = threadIdx.x;
    const int wv  = t >> 6;              // kq 0..3
    const int b0  = t & 63;

    // stage w2 octet: global [c2][c1][k] (coalesced read) -> [k][c1][c2i]
    for (int idx = t; idx < K2_*C1_*8; idx += 256) {
        const int c2i = idx / (C1_*K2_);
        const int rem = idx - c2i*(C1_*K2_);
        const int c1  = rem / K2_;
        const int k   = rem - c1*K2_;
        w2s[(k*C1_ + c1)*8 + c2i] = w2[(c2o*8 + c2i)*(C1_*K2_) + rem];
    }
    __syncthreads();

    float acc[8][2];
    #pragma unroll
    for (int c = 0; c < 8; ++c) { acc[c][0] = 0.f; acc[c][1] = 0.f; }

    const int cb = wv*32;
    for (int c1i = 0; c1i < 32; ++c1i) {
        const int c1 = cb + c1i;
        const float* hbase = &h1g[(c1*HR + l)*B_];   // rows l..l+4 = pos l-2..l+2
        #pragma unroll
        for (int k = 0; k < K2_; ++k) {
            const float h0 = hbase[k*B_ + b0];
            const float h1 = hbase[k*B_ + b0 + 64];
            const float4* wp = (const float4*)&w2s[(k*C1_ + c1)*8];
            const float4 wa = wp[0], wb = wp[1];
            acc[0][0] += wa.x*h0;  acc[0][1] += wa.x*h1;
            acc[1][0] += wa.y*h0;  acc[1][1] += wa.y*h1;
            acc[2][0] += wa.z*h0;  acc[2][1] += wa.z*h1;
            acc[3][0] += wa.w*h0;  acc[3][1] += wa.w*h1;
            acc[4][0] += wb.x*h0;  acc[4][1] += wb.x*h1;
            acc[5][0] += wb.y*h0;  acc[5][1] += wb.y*h1;
            acc[6][0] += wb.z*h0;  acc[6][1] += wb.z*h1;
            acc[7][0] += wb.w*h0;  acc[7][1] += wb.w*h1;
        }
    }

    // split-K reduce via LDS
    #pragma unroll
    for (int c = 0; c < 8; ++c) {
        red[(wv*8 + c)*B_ + b0]      = acc[c][0];
        red[(wv*8 + c)*B_ + b0 + 64] = acc[c][1];
    }
    __syncthreads();

    for (int u = t; u < 8*B_; u += 256) {
        const int c2i = u >> 7;
        const int bb  = u & 127;
        float s = red[(0*8 + c2i)*B_ + bb] + red[(1*8 + c2i)*B_ + bb]
                + red[(2*8 + c2i)*B_ + bb] + red[(3*8 + c2i)*B_ + bb];
        s += b2[c2o*8 + c2i];
        featT[(l*C2_ + c2o*8 + c2i)*B_ + bb] = fmaxf(s, 0.f);
    }
}

// ---------------------------------------------------------------------------
// Kernel B: EXACT round-9 reg_kernel.
// ---------------------------------------------------------------------------
__global__ __launch_bounds__(256) void reg_kernel(
    const float* __restrict__ featT,
    const float* __restrict__ rw, const float* __restrict__ rb,
    float* __restrict__ part)
{
    __shared__ float ws[64*64];     // 16KB
    __shared__ float red0[256], red1[256];
    const int t  = threadIdx.x;
    const int b0 = t & 63;
    const int wv = t >> 6;          // 0..3
    const int bid = blockIdx.x;

    float acc0 = 0.f, acc1 = 0.f;

    if (bid == NPAIR) {             // first order + const
        const int u0 = wv * (FEAT/4);
        for (int u = u0; u < u0 + FEAT/4; ++u) {
            const float w = rw[1 + u];              // wave-uniform -> s_load
            acc0 += featT[u*B_ + b0]      * w;      // coalesced
            acc1 += featT[u*B_ + b0 + 64] * w;
        }
        if (wv == 0) { const float c = rw[0] + rb[0]; acc0 += c; acc1 += c; }
    } else {
        int i = 0, r = bid;
        while (r >= NPOS - i) { r -= NPOS - i; ++i; }
        const int j = i + 1 + r;

        const int stride = (NPOS - i) * 64;
        const int base   = 1 + FEAT + 4096*(NPOS*i - (i*(i-1))/2)
                         + (j - i - 1)*64;

        // stage W_ij (64 rows x 64 q) coalesced over q
        #pragma unroll
        for (int k = 0; k < 16; ++k) {
            const int idx = t + k*256;
            ws[idx] = rw[base + (idx >> 6)*stride + (idx & 63)];
        }
        __syncthreads();

        const int p0 = wv * 16;
        float sp0[16], sp1[16];
        #pragma unroll
        for (int pp = 0; pp < 16; ++pp) { sp0[pp] = 0.f; sp1[pp] = 0.f; }

        const float* fj = &featT[j*64*B_ + b0];
        #pragma unroll 4
        for (int g = 0; g < 16; ++g) {
            const float f00 = fj[(g*4+0)*B_],      f01 = fj[(g*4+1)*B_],
                        f02 = fj[(g*4+2)*B_],      f03 = fj[(g*4+3)*B_];
            const float f10 = fj[(g*4+0)*B_ + 64], f11 = fj[(g*4+1)*B_ + 64],
                        f12 = fj[(g*4+2)*B_ + 64], f13 = fj[(g*4+3)*B_ + 64];
            #pragma unroll
            for (int pp = 0; pp < 16; ++pp) {
                const float4 w = *(const float4*)&ws[(p0 + pp)*64 + g*4];
                sp0[pp] += w.x*f00 + w.y*f01 + w.z*f02 + w.w*f03;
                sp1[pp] += w.x*f10 + w.y*f11 + w.z*f12 + w.w*f13;
            }
        }

        const float* fi = &featT[(i*64 + p0)*B_ + b0];
        #pragma unroll
        for (int pp = 0; pp < 16; ++pp) {
            acc0 += fi[pp*B_]      * sp0[pp];
            acc1 += fi[pp*B_ + 64] * sp1[pp];
        }
    }

    red0[t] = acc0;
    red1[t] = acc1;
    __syncthreads();
    if (t < B_) {
        const int bb = t & 63;
        const float* rr = (t < 64) ? red0 : red1;
        part[bid*B_ + t] = (rr[bb] + rr[64+bb]) + (rr[128+bb] + rr[192+bb]);
    }
}

// ---------------------------------------------------------------------------
// finalize: out[b] = sum over 326 partials (coalesced, 4-way ILP)
// ---------------------------------------------------------------------------
__global__ __launch_bounds__(128) void fin_kernel(
    const float* __restrict__ part, float* __restrict__ out)
{
    const int b = threadIdx.x;
    float s0 = 0.f, s1 = 0.f, s2 = 0.f, s3 = 0.f;
    int p = 0;
    for (; p + 4 <= NPAIR + 1; p += 4) {
        s0 += part[(p+0)*B_ + b];
        s1 += part[(p+1)*B_ + b];
        s2 += part[(p+2)*B_ + b];
        s3 += part[(p+3)*B_ + b];
    }
    for (; p < NPAIR + 1; ++p) s0 += part[p*B_ + b];
    out[b] = (s0 + s1) + (s2 + s3);
}

// ---------------------------------------------------------------------------
extern "C" void kernel_launch(void* const* d_in, const int* in_sizes, int n_in,
                              void* d_out, int out_size, void* d_ws, size_t ws_size,
                              hipStream_t stream)
{
    const int*   x  = (const int*)  d_in[0];
    const float* w1 = (const float*)d_in[1];
    const float* b1 = (const float*)d_in[2];
    const float* w2 = (const float*)d_in[3];
    const float* b2 = (const float*)d_in[4];
    const float* rw = (const float*)d_in[5];
    const float* rb = (const float*)d_in[6];
    float* out   = (float*)d_out;
    float* h1g   = (float*)d_ws;                        // 1,966,080 B
    float* featT = (float*)((char*)d_ws + 1966080);     //   851,968 B
    float* part  = (float*)((char*)d_ws + 2818048);     //   166,912 B

    s_kernel  <<<dim3(120), dim3(128), 0, stream>>>(x, w1, b1, h1g);
    g_kernel  <<<dim3(208), dim3(256), 0, stream>>>(h1g, w2, b2, featT);
    reg_kernel<<<dim3(NPAIR+1), dim3(256), 0, stream>>>(featT, rw, rb, part);
    fin_kernel<<<dim3(1), dim3(128), 0, stream>>>(part, out);
}

// Round 13
// 114.686 us; speedup vs baseline: 1.2317x; 1.1065x over previous
//
#include <hip/hip_runtime.h>

#define B_   128
#define L_   26
#define C1_  128
#define C2_  64
#define K1_  7
#define K2_  5
#define NPOS 25
#define FEAT (L_*C2_)            // 1664
#define NPAIR (NPOS*(NPOS+1)/2)  // 325

#define HROW 132
#define WROW 644

// ---------------------------------------------------------------------------
// Kernel A: conv1 -> conv2 -> featT[u][b]  (u = l*64+c2; b innermost =
// lane-coalesced for kernel B). EXACT round-9 version (replication run).
// ---------------------------------------------------------------------------
__global__ __launch_bounds__(256) void conv_kernel(
    const int*   __restrict__ x,
    const float* __restrict__ w1, const float* __restrict__ b1,
    const float* __restrict__ w2, const float* __restrict__ b2,
    float* __restrict__ featT)
{
    __shared__ float h1s[30*HROW];          // 15840B
    __shared__ float w2s[16*WROW];          // 41216B
    __shared__ float w1s[4*K1_*C1_];        // [nt][k][c1], 14336B
    __shared__ int   xs[L_];

    const int bid = blockIdx.x;
    const int b   = bid >> 2;
    const int c2t = bid & 3;
    const int t   = threadIdx.x;

    if (t < L_) xs[t] = x[b*L_ + t];
    if (t < HROW) { h1s[0*HROW+t] = 0.f; h1s[1*HROW+t] = 0.f;
                    h1s[28*HROW+t] = 0.f; h1s[29*HROW+t] = 0.f; }

    for (int i = t; i < C1_*4*K1_; i += 256) {
        const int c1  = i / (4*K1_);
        const int rem = i - c1*(4*K1_);
        const int nt  = rem / K1_;
        const int k   = rem - nt*K1_;
        w1s[(nt*K1_ + k)*C1_ + c1] = w1[i];
    }

    {
        const float* src = w2 + c2t*16*C1_*K2_;
        for (int idx = t; idx < 16*C1_*K2_; idx += 256) {
            const int c2i = idx / (C1_*K2_);
            const int rem = idx - c2i*(C1_*K2_);
            const int c1  = rem / K2_;
            const int k   = rem - c1*K2_;
            w2s[c2i*WROW + k*C1_ + c1] = src[idx];
        }
    }
    __syncthreads();

    for (int idx = t; idx < C1_*L_; idx += 256) {
        const int c1 = idx & 127;
        const int l  = idx >> 7;
        float s = b1[c1];
        #pragma unroll
        for (int k = 0; k < K1_; ++k) {
            const int pos = l + k - 3;
            if (pos >= 0 && pos < L_)
                s += w1s[(xs[pos]*K1_ + k)*C1_ + c1];
        }
        h1s[(l+2)*HROW + c1] = fmaxf(s, 0.f);
    }
    __syncthreads();

    if (t < 16*13) {
        const int c2i = t & 15;
        const int lg  = t >> 4;
        const int l0  = 2*lg, l1 = 2*lg + 1;
        float a0 = 0.f, a1 = 0.f, a2 = 0.f, a3 = 0.f;
        #pragma unroll
        for (int k = 0; k < K2_; ++k) {
            const float4* wrow = (const float4*)&w2s[c2i*WROW + k*C1_];
            const float4* h0r  = (const float4*)&h1s[(l0 + k)*HROW];
            const float4* h1r  = (const float4*)&h1s[(l1 + k)*HROW];
            #pragma unroll
            for (int cq = 0; cq < 32; cq += 2) {
                const float4 w0 = wrow[cq],  w1v = wrow[cq+1];
                const float4 x0 = h0r[cq],   x1 = h0r[cq+1];
                const float4 y0 = h1r[cq],   y1 = h1r[cq+1];
                a0 += w0.x*x0.x + w0.y*x0.y + w0.z*x0.z + w0.w*x0.w;
                a1 += w1v.x*x1.x + w1v.y*x1.y + w1v.z*x1.z + w1v.w*x1.w;
                a2 += w0.x*y0.x + w0.y*y0.y + w0.z*y0.z + w0.w*y0.w;
                a3 += w1v.x*y1.x + w1v.y*y1.y + w1v.z*y1.z + w1v.w*y1.w;
            }
        }
        const int   c2  = c2t*16 + c2i;
        const float bb  = b2[c2];
        featT[(l0*C2_ + c2)*B_ + b] = fmaxf(a0 + a1 + bb, 0.f);   // [u][b]
        featT[(l1*C2_ + c2)*B_ + b] = fmaxf(a2 + a3 + bb, 0.f);
    }
}

// ---------------------------------------------------------------------------
// Kernel B: EXACT round-9 version.
// ---------------------------------------------------------------------------
__global__ __launch_bounds__(256) void reg_kernel(
    const float* __restrict__ featT,
    const float* __restrict__ rw, const float* __restrict__ rb,
    float* __restrict__ part)
{
    __shared__ float ws[64*64];     // 16KB
    __shared__ float red0[256], red1[256];
    const int t  = threadIdx.x;
    const int b0 = t & 63;
    const int wv = t >> 6;          // 0..3
    const int bid = blockIdx.x;

    float acc0 = 0.f, acc1 = 0.f;

    if (bid == NPAIR) {             // first order + const
        const int u0 = wv * (FEAT/4);
        for (int u = u0; u < u0 + FEAT/4; ++u) {
            const float w = rw[1 + u];              // wave-uniform -> s_load
            acc0 += featT[u*B_ + b0]      * w;      // coalesced
            acc1 += featT[u*B_ + b0 + 64] * w;
        }
        if (wv == 0) { const float c = rw[0] + rb[0]; acc0 += c; acc1 += c; }
    } else {
        int i = 0, r = bid;
        while (r >= NPOS - i) { r -= NPOS - i; ++i; }
        const int j = i + 1 + r;

        const int stride = (NPOS - i) * 64;
        const int base   = 1 + FEAT + 4096*(NPOS*i - (i*(i-1))/2)
                         + (j - i - 1)*64;

        // stage W_ij (64 rows x 64 q) coalesced over q
        #pragma unroll
        for (int k = 0; k < 16; ++k) {
            const int idx = t + k*256;
            ws[idx] = rw[base + (idx >> 6)*stride + (idx & 63)];
        }
        __syncthreads();

        const int p0 = wv * 16;
        float sp0[16], sp1[16];
        #pragma unroll
        for (int pp = 0; pp < 16; ++pp) { sp0[pp] = 0.f; sp1[pp] = 0.f; }

        const float* fj = &featT[j*64*B_ + b0];
        #pragma unroll 4
        for (int g = 0; g < 16; ++g) {
            const float f00 = fj[(g*4+0)*B_],      f01 = fj[(g*4+1)*B_],
                        f02 = fj[(g*4+2)*B_],      f03 = fj[(g*4+3)*B_];
            const float f10 = fj[(g*4+0)*B_ + 64], f11 = fj[(g*4+1)*B_ + 64],
                        f12 = fj[(g*4+2)*B_ + 64], f13 = fj[(g*4+3)*B_ + 64];
            #pragma unroll
            for (int pp = 0; pp < 16; ++pp) {
                const float4 w = *(const float4*)&ws[(p0 + pp)*64 + g*4];
                sp0[pp] += w.x*f00 + w.y*f01 + w.z*f02 + w.w*f03;
                sp1[pp] += w.x*f10 + w.y*f11 + w.z*f12 + w.w*f13;
            }
        }

        const float* fi = &featT[(i*64 + p0)*B_ + b0];
        #pragma unroll
        for (int pp = 0; pp < 16; ++pp) {
            acc0 += fi[pp*B_]      * sp0[pp];
            acc1 += fi[pp*B_ + 64] * sp1[pp];
        }
    }

    red0[t] = acc0;
    red1[t] = acc1;
    __syncthreads();
    if (t < B_) {
        const int bb = t & 63;
        const float* rr = (t < 64) ? red0 : red1;
        part[bid*B_ + t] = (rr[bb] + rr[64+bb]) + (rr[128+bb] + rr[192+bb]);
    }
}

// ---------------------------------------------------------------------------
// finalize: out[b] = sum over 326 partials (coalesced, 4-way ILP)
// ---------------------------------------------------------------------------
__global__ __launch_bounds__(128) void fin_kernel(
    const float* __restrict__ part, float* __restrict__ out)
{
    const int b = threadIdx.x;
    float s0 = 0.f, s1 = 0.f, s2 = 0.f, s3 = 0.f;
    int p = 0;
    for (; p + 4 <= NPAIR + 1; p += 4) {
        s0 += part[(p+0)*B_ + b];
        s1 += part[(p+1)*B_ + b];
        s2 += part[(p+2)*B_ + b];
        s3 += part[(p+3)*B_ + b];
    }
    for (; p < NPAIR + 1; ++p) s0 += part[p*B_ + b];
    out[b] = (s0 + s1) + (s2 + s3);
}

// ---------------------------------------------------------------------------
extern "C" void kernel_launch(void* const* d_in, const int* in_sizes, int n_in,
                              void* d_out, int out_size, void* d_ws, size_t ws_size,
                              hipStream_t stream)
{
    const int*   x  = (const int*)  d_in[0];
    const float* w1 = (const float*)d_in[1];
    const float* b1 = (const float*)d_in[2];
    const float* w2 = (const float*)d_in[3];
    const float* b2 = (const float*)d_in[4];
    const float* rw = (const float*)d_in[5];
    const float* rb = (const float*)d_in[6];
    float* out   = (float*)d_out;
    float* featT = (float*)d_ws;                     // 851968 B
    float* part  = (float*)((char*)d_ws + 851968);   // 166912 B

    conv_kernel<<<dim3(512), dim3(256), 0, stream>>>(x, w1, b1, w2, b2, featT);
    reg_kernel <<<dim3(NPAIR+1), dim3(256), 0, stream>>>(featT, rw, rb, part);
    fin_kernel <<<dim3(1), dim3(128), 0, stream>>>(part, out);
}